// Round 8
// baseline (126.612 us; speedup 1.0000x reference)
//
#include <hip/hip_runtime.h>
#include <math.h>

#define CUTOFF_F 5.0f
#define MIN_DIST_F 0.01f
#define EPS_D 1e-7

typedef float f32x4 __attribute__((ext_vector_type(4)));

// ---------------------------------------------------------------------------
// Single fused kernel. Block = (b, i). Each block redundantly computes the
// per-system prep (3x3 inverse in double, wrapped positions, 27 cartesian
// shifts) directly into LDS — removes the separate prep kernel, its launch
// bubble, and the workspace round-trip. Fill loop = round-2 structure
// (best measured: direct float4 stores, no mid-loop barrier).
// Output: [diff 3*D1][dist D1][mask D1], D1 = B*N*N*27.
// ---------------------------------------------------------------------------
__global__ __launch_bounds__(256) void bnl_fused(const float* __restrict__ pos,
                                                 const float* __restrict__ cell,
                                                 float* __restrict__ out,
                                                 int B, int N) {
    extern __shared__ float lds[];          // [N*3] wp row, then [81] sc
    float* lwp = lds;
    float* lsc = lds + N * 3;

    int b = blockIdx.x / N;
    int i = blockIdx.x - b * N;

    // --- per-block prep (uniform cell -> scalar-cached loads) ---
    const float* c = cell + b * 9;
    double a00 = c[0], a01 = c[1], a02 = c[2];
    double a10 = c[3], a11 = c[4], a12 = c[5];
    double a20 = c[6], a21 = c[7], a22 = c[8];
    {
        double co00 =  (a11 * a22 - a12 * a21);
        double co01 = -(a10 * a22 - a12 * a20);
        double co02 =  (a10 * a21 - a11 * a20);
        double det = a00 * co00 + a01 * co01 + a02 * co02;
        double id = 1.0 / det;
        double m00 = co00 * id;
        double m01 = -(a01 * a22 - a02 * a21) * id;
        double m02 =  (a01 * a12 - a02 * a11) * id;
        double m10 = co01 * id;
        double m11 =  (a00 * a22 - a02 * a20) * id;
        double m12 = -(a00 * a12 - a02 * a10) * id;
        double m20 = co02 * id;
        double m21 = -(a00 * a21 - a01 * a20) * id;
        double m22 =  (a00 * a11 - a01 * a10) * id;

        // wrapped positions for this system -> LDS
        for (int n = threadIdx.x; n < N; n += blockDim.x) {
            const float* p = pos + ((size_t)b * N + n) * 3;
            double p0 = p[0], p1 = p[1], p2 = p[2];
            double s0 = p0 * m00 + p1 * m10 + p2 * m20 + EPS_D;
            double s1 = p0 * m01 + p1 * m11 + p2 * m21 + EPS_D;
            double s2 = p0 * m02 + p1 * m12 + p2 * m22 + EPS_D;
            s0 -= floor(s0); s1 -= floor(s1); s2 -= floor(s2);
            s0 -= EPS_D; s1 -= EPS_D; s2 -= EPS_D;
            lwp[n * 3 + 0] = (float)(s0 * a00 + s1 * a10 + s2 * a20);
            lwp[n * 3 + 1] = (float)(s0 * a01 + s1 * a11 + s2 * a21);
            lwp[n * 3 + 2] = (float)(s0 * a02 + s1 * a12 + s2 * a22);
        }
        // 27 cartesian shift vectors -> LDS (one float per thread 0..80)
        if (threadIdx.x < 81) {
            int s  = threadIdx.x / 3;
            int cc = threadIdx.x - s * 3;
            double sx = (double)(s / 9 - 1);
            double sy = (double)((s / 3) % 3 - 1);
            double sz = (double)(s % 3 - 1);
            // column cc of cell rows
            double col0 = (cc == 0) ? a00 : (cc == 1) ? a01 : a02;
            double col1 = (cc == 0) ? a10 : (cc == 1) ? a11 : a12;
            double col2 = (cc == 0) ? a20 : (cc == 1) ? a21 : a22;
            lsc[threadIdx.x] = (float)(sx * col0 + sy * col1 + sz * col2);
        }
    }
    __syncthreads();

    float pix = lwp[i * 3 + 0];
    float piy = lwp[i * 3 + 1];
    float piz = lwp[i * 3 + 2];

    size_t D1  = (size_t)B * N * N * 27;
    size_t row = (size_t)(b * N + i) * N * 27;
    float* diff_out = out + row * 3;
    float* dist_out = out + 3 * D1 + row;
    float* mask_out = out + 4 * D1 + row;

    int NQ = (N * 27) >> 2;                 // quads per row (N%4==0)

    for (int q = threadIdx.x; q < NQ; q += blockDim.x) {
        float dv[12], tv[4], mv[4];
        int p0 = q << 2;
        unsigned j = (unsigned)p0 / 27u;
        unsigned s = (unsigned)p0 - j * 27u;
#pragma unroll
        for (int k = 0; k < 4; ++k) {
            float dx = lwp[j * 3 + 0] + lsc[s * 3 + 0] - pix;
            float dy = lwp[j * 3 + 1] + lsc[s * 3 + 1] - piy;
            float dz = lwp[j * 3 + 2] + lsc[s * 3 + 2] - piz;
            float dist = sqrtf(dx * dx + dy * dy + dz * dz);
            bool m = (dist < CUTOFF_F) && (dist > MIN_DIST_F);
            dv[k * 3 + 0] = m ? dx : 0.0f;
            dv[k * 3 + 1] = m ? dy : 0.0f;
            dv[k * 3 + 2] = m ? dz : 0.0f;
            tv[k] = m ? dist : 0.0f;
            mv[k] = m ? 1.0f : 0.0f;
            ++s;
            if (s == 27u) { s = 0u; ++j; }
        }
        f32x4* dp = reinterpret_cast<f32x4*>(diff_out + (size_t)p0 * 3);
        dp[0] = (f32x4){dv[0], dv[1], dv[2],  dv[3]};
        dp[1] = (f32x4){dv[4], dv[5], dv[6],  dv[7]};
        dp[2] = (f32x4){dv[8], dv[9], dv[10], dv[11]};
        *reinterpret_cast<f32x4*>(dist_out + (size_t)p0) = (f32x4){tv[0], tv[1], tv[2], tv[3]};
        *reinterpret_cast<f32x4*>(mask_out + (size_t)p0) = (f32x4){mv[0], mv[1], mv[2], mv[3]};
    }
}

extern "C" void kernel_launch(void* const* d_in, const int* in_sizes, int n_in,
                              void* d_out, int out_size, void* d_ws, size_t ws_size,
                              hipStream_t stream) {
    const float* pos  = (const float*)d_in[0];   // [B*N,3]
    const float* cell = (const float*)d_in[1];   // [B,3,3]
    int B = in_sizes[1] / 9;
    int N = in_sizes[0] / (3 * B);

    size_t lds_bytes = ((size_t)N * 3 + 81) * sizeof(float);
    bnl_fused<<<B * N, 256, lds_bytes, stream>>>(pos, cell, (float*)d_out, B, N);
}

// Round 9
// 114.191 us; speedup vs baseline: 1.1088x; 1.1088x over previous
//
#include <hip/hip_runtime.h>
#include <math.h>

#define CUTOFF_F 5.0f
#define MIN_DIST_F 0.01f
#define EPS_D 1e-7

// ---------------------------------------------------------------------------
// Prep: per-system 3x3 inverse (double), wrapped positions, cartesian shifts.
// wp[b*N+n][3] (f32), sc[b*27+s][3] (f32) into workspace.
// ---------------------------------------------------------------------------
__global__ void bnl_prep(const float* __restrict__ pos,
                         const float* __restrict__ cell,
                         float* __restrict__ wp,
                         float* __restrict__ sc,
                         int B, int N) {
    int tid = blockIdx.x * blockDim.x + threadIdx.x;
    int nthreads = gridDim.x * blockDim.x;

    for (int t = tid; t < B * 27; t += nthreads) {
        int b = t / 27, s = t - b * 27;
        int sx = s / 9 - 1;
        int sy = (s / 3) % 3 - 1;
        int sz = s - (s / 3) * 3 - 1;
        const float* c = cell + b * 9;
        sc[t * 3 + 0] = (float)((double)sx * c[0] + (double)sy * c[3] + (double)sz * c[6]);
        sc[t * 3 + 1] = (float)((double)sx * c[1] + (double)sy * c[4] + (double)sz * c[7]);
        sc[t * 3 + 2] = (float)((double)sx * c[2] + (double)sy * c[5] + (double)sz * c[8]);
    }

    int total = B * N;
    for (int n = tid; n < total; n += nthreads) {
        int b = n / N;
        const float* c = cell + b * 9;
        double a00 = c[0], a01 = c[1], a02 = c[2];
        double a10 = c[3], a11 = c[4], a12 = c[5];
        double a20 = c[6], a21 = c[7], a22 = c[8];
        double co00 =  (a11 * a22 - a12 * a21);
        double co01 = -(a10 * a22 - a12 * a20);
        double co02 =  (a10 * a21 - a11 * a20);
        double det = a00 * co00 + a01 * co01 + a02 * co02;
        double id = 1.0 / det;
        double m00 = co00 * id;
        double m01 = -(a01 * a22 - a02 * a21) * id;
        double m02 =  (a01 * a12 - a02 * a11) * id;
        double m10 = co01 * id;
        double m11 =  (a00 * a22 - a02 * a20) * id;
        double m12 = -(a00 * a12 - a02 * a10) * id;
        double m20 = co02 * id;
        double m21 = -(a00 * a21 - a01 * a20) * id;
        double m22 =  (a00 * a11 - a01 * a10) * id;

        double p0 = pos[n * 3 + 0], p1 = pos[n * 3 + 1], p2 = pos[n * 3 + 2];
        double s0 = p0 * m00 + p1 * m10 + p2 * m20 + EPS_D;
        double s1 = p0 * m01 + p1 * m11 + p2 * m21 + EPS_D;
        double s2 = p0 * m02 + p1 * m12 + p2 * m22 + EPS_D;
        s0 -= floor(s0); s1 -= floor(s1); s2 -= floor(s2);
        s0 -= EPS_D; s1 -= EPS_D; s2 -= EPS_D;
        wp[n * 3 + 0] = (float)(s0 * a00 + s1 * a10 + s2 * a20);
        wp[n * 3 + 1] = (float)(s0 * a01 + s1 * a11 + s2 * a21);
        wp[n * 3 + 2] = (float)(s0 * a02 + s1 * a12 + s2 * a22);
    }
}

// ---------------------------------------------------------------------------
// Fill, pair-centric: block = (b,i). Stage wp[b] row + sc[b] in LDS.
// Each lane handles 4 consecutive pairs p = j*27+s, computes geometry ONCE per
// pair, writes diff (3x float4), dist (float4), mask (float4) — all aligned,
// dense, coalesced. Output: [diff 3*D1][dist D1][mask D1], D1 = B*N*N*27.
// Best-measured structure (114.5 us): direct stores, no mid-loop barrier.
// ---------------------------------------------------------------------------
__global__ __launch_bounds__(256) void bnl_fill2(const float* __restrict__ wp,
                                                 const float* __restrict__ sc,
                                                 float* __restrict__ out,
                                                 int B, int N) {
    extern __shared__ float lds[];          // [N*3] wp row, then [81] sc
    float* lwp = lds;
    float* lsc = lds + N * 3;

    int b = blockIdx.x / N;
    int i = blockIdx.x - b * N;

    const float* wrow = wp + (size_t)b * N * 3;
    int nf4 = (N * 3) >> 2;
    for (int t = threadIdx.x; t < nf4; t += blockDim.x)
        reinterpret_cast<float4*>(lwp)[t] = reinterpret_cast<const float4*>(wrow)[t];
    for (int t = (nf4 << 2) + threadIdx.x; t < N * 3; t += blockDim.x)
        lwp[t] = wrow[t];
    for (int t = threadIdx.x; t < 81; t += blockDim.x)
        lsc[t] = sc[(size_t)b * 81 + t];
    __syncthreads();

    float pix = lwp[i * 3 + 0];
    float piy = lwp[i * 3 + 1];
    float piz = lwp[i * 3 + 2];

    size_t D1  = (size_t)B * N * N * 27;
    size_t row = (size_t)(b * N + i) * N * 27;   // pair-index base of this row
    float* diff_out = out + row * 3;
    float* dist_out = out + 3 * D1 + row;
    float* mask_out = out + 4 * D1 + row;

    int NP = N * 27;           // pairs in this row
    int NQ = NP >> 2;          // quads (N*27 divisible by 4 when N%4==0)

    for (int q = threadIdx.x; q < NQ; q += blockDim.x) {
        float dv[12], tv[4], mv[4];
        int p0 = q << 2;
#pragma unroll
        for (int k = 0; k < 4; ++k) {
            unsigned p = (unsigned)(p0 + k);
            unsigned j = p / 27u;
            unsigned s = p - j * 27u;
            float dx = lwp[j * 3 + 0] + lsc[s * 3 + 0] - pix;
            float dy = lwp[j * 3 + 1] + lsc[s * 3 + 1] - piy;
            float dz = lwp[j * 3 + 2] + lsc[s * 3 + 2] - piz;
            float dist = sqrtf(dx * dx + dy * dy + dz * dz);
            bool m = (dist < CUTOFF_F) && (dist > MIN_DIST_F);
            dv[k * 3 + 0] = m ? dx : 0.0f;
            dv[k * 3 + 1] = m ? dy : 0.0f;
            dv[k * 3 + 2] = m ? dz : 0.0f;
            tv[k] = m ? dist : 0.0f;
            mv[k] = m ? 1.0f : 0.0f;
        }
        float4* dp = reinterpret_cast<float4*>(diff_out + (size_t)p0 * 3);
        dp[0] = make_float4(dv[0], dv[1], dv[2],  dv[3]);
        dp[1] = make_float4(dv[4], dv[5], dv[6],  dv[7]);
        dp[2] = make_float4(dv[8], dv[9], dv[10], dv[11]);
        *reinterpret_cast<float4*>(dist_out + p0) = make_float4(tv[0], tv[1], tv[2], tv[3]);
        *reinterpret_cast<float4*>(mask_out + p0) = make_float4(mv[0], mv[1], mv[2], mv[3]);
    }
}

extern "C" void kernel_launch(void* const* d_in, const int* in_sizes, int n_in,
                              void* d_out, int out_size, void* d_ws, size_t ws_size,
                              hipStream_t stream) {
    const float* pos  = (const float*)d_in[0];   // [B*N,3]
    const float* cell = (const float*)d_in[1];   // [B,3,3]
    int B = in_sizes[1] / 9;
    int N = in_sizes[0] / (3 * B);

    float* wp = (float*)d_ws;                    // B*N*3 floats
    float* sc = wp + (size_t)B * N * 3;          // B*27*3 floats

    bnl_prep<<<8, 256, 0, stream>>>(pos, cell, wp, sc, B, N);

    size_t lds_bytes = ((size_t)N * 3 + 81) * sizeof(float);
    bnl_fill2<<<B * N, 256, lds_bytes, stream>>>(wp, sc, (float*)d_out, B, N);
}